// Round 2
// baseline (440.298 us; speedup 1.0000x reference)
//
#include <hip/hip_runtime.h>
#include <math.h>

// Problem constants (B=2, T=8, N=128 -> S=1024, Hd=64, H=8)
#define S_TOK 1024
#define JTILES 4          // 1024 / 256
#define EPS_F 1e-6f

// e3nn 'integral' normalization constants
#define C0_F 0.28209479177387814f   // 0.5/sqrt(pi)
#define C1_F 0.4886025119029199f    // sqrt(3/(4pi))
#define C2_F 0.6307831305050401f    // sqrt(5/(4pi))
#define SQRT3_F 1.7320508075688772f

__device__ __forceinline__ float silu_f(float x) {
    return x / (1.0f + __expf(-x));
}

__global__ __launch_bounds__(256, 4)
void shab_f32_kernel(const float* __restrict__ coords,
                     const float* __restrict__ w1, const float* __restrict__ b1,
                     const float* __restrict__ w2, const float* __restrict__ b2,
                     const float* __restrict__ w3, const float* __restrict__ b3,
                     float* __restrict__ out)
{
    // block -> (b, i, j_tile); thread -> j within tile
    const int bid = blockIdx.x;
    const int b   = bid / (S_TOK * JTILES);
    const int rem = bid % (S_TOK * JTILES);
    const int i   = rem / JTILES;
    const int j   = (rem % JTILES) * 256 + threadIdx.x;

    const float* cb = coords + (size_t)b * S_TOK * 3;
    // c_i is block-uniform (scalar path); c_j per-thread
    const float xi = cb[i * 3 + 0], yi = cb[i * 3 + 1], zi = cb[i * 3 + 2];
    const float xj = cb[j * 3 + 0], yj = cb[j * 3 + 1], zj = cb[j * 3 + 2];

    // rel = c_i - c_j  (reference: rel[b,i,j] = c[b,i] - c[b,j])
    const float rx = xi - xj, ry = yi - yj, rz = zi - zj;
    const float n2 = rx * rx + ry * ry + rz * rz;
    const float nrm = sqrtf(n2);
    const float inv1 = 1.0f / (nrm + EPS_F);
    float ux = rx * inv1, uy = ry * inv1, uz = rz * inv1;
    // e3nn normalize=True re-normalization (zero stays zero)
    const float un = sqrtf(ux * ux + uy * uy + uz * uz);
    const float inv2 = 1.0f / fmaxf(un, EPS_F);
    const float x = ux * inv2, y = uy * inv2, z = uz * inv2;

    // real spherical harmonics l=0..2, e3nn component order, integral norm
    float sh[9];
    sh[0] = C0_F;
    sh[1] = C1_F * x;
    sh[2] = C1_F * y;
    sh[3] = C1_F * z;
    sh[4] = C2_F * SQRT3_F * x * z;
    sh[5] = C2_F * SQRT3_F * x * y;
    sh[6] = C2_F * (y * y - 0.5f * (x * x + z * z));
    sh[7] = C2_F * SQRT3_F * y * z;
    sh[8] = C2_F * (SQRT3_F * 0.5f) * (z * z - x * x);

    // ---- layer 1: 9 -> 64, silu ----
    float h1[64];
    #pragma unroll
    for (int c = 0; c < 64; ++c) h1[c] = b1[c];
    #pragma unroll
    for (int k = 0; k < 9; ++k) {
        const float s = sh[k];
        #pragma unroll
        for (int c = 0; c < 64; ++c)
            h1[c] = fmaf(s, w1[k * 64 + c], h1[c]);
    }
    #pragma unroll
    for (int c = 0; c < 64; ++c) h1[c] = silu_f(h1[c]);

    // ---- layer 2 (64 -> 64, silu) fused with layer 3 (64 -> 8) ----
    float o[8];
    #pragma unroll
    for (int h = 0; h < 8; ++h) o[h] = b3[h];

    for (int chunk = 0; chunk < 4; ++chunk) {   // 16 columns of h2 at a time
        float h2c[16];
        #pragma unroll
        for (int cc = 0; cc < 16; ++cc) h2c[cc] = b2[chunk * 16 + cc];
        #pragma unroll
        for (int k = 0; k < 64; ++k) {
            const float hk = h1[k];
            #pragma unroll
            for (int cc = 0; cc < 16; ++cc)
                h2c[cc] = fmaf(hk, w2[k * 64 + chunk * 16 + cc], h2c[cc]);
        }
        #pragma unroll
        for (int cc = 0; cc < 16; ++cc) {
            const float v = silu_f(h2c[cc]);
            #pragma unroll
            for (int h = 0; h < 8; ++h)
                o[h] = fmaf(v, w3[(chunk * 16 + cc) * 8 + h], o[h]);
        }
    }

    // out[b][h][i][j], h-stride = S*S
    const size_t base = ((size_t)b * 8) * S_TOK * S_TOK + (size_t)i * S_TOK + j;
    #pragma unroll
    for (int h = 0; h < 8; ++h)
        out[base + (size_t)h * S_TOK * S_TOK] = o[h];
}

extern "C" void kernel_launch(void* const* d_in, const int* in_sizes, int n_in,
                              void* d_out, int out_size, void* d_ws, size_t ws_size,
                              hipStream_t stream)
{
    const float* coords = (const float*)d_in[0];
    const float* w1 = (const float*)d_in[1];
    const float* b1 = (const float*)d_in[2];
    const float* w2 = (const float*)d_in[3];
    const float* b2 = (const float*)d_in[4];
    const float* w3 = (const float*)d_in[5];
    const float* b3 = (const float*)d_in[6];
    float* out = (float*)d_out;

    const int B = in_sizes[0] / (S_TOK * 3);   // = 2
    dim3 grid(B * S_TOK * JTILES);
    shab_f32_kernel<<<grid, 256, 0, stream>>>(coords, w1, b1, w2, b2, w3, b3, out);
}

// Round 4
// 273.579 us; speedup vs baseline: 1.6094x; 1.6094x over previous
//
#include <hip/hip_runtime.h>
#include <math.h>

// Problem constants (B=2, T=8, N=128 -> S=1024, Hd=64, H=8)
#define S_TOK 1024

// e3nn 'integral' normalization constants
#define C0_F  0.28209479177387814f   // 0.5/sqrt(pi)
#define C1_F  0.4886025119029199f    // sqrt(3/(4pi))
#define C2_F  0.6307831305050401f    // sqrt(5/(4pi))
#define C2S3  1.0925484305920792f    // C2*sqrt(3)
#define C2H3  0.5462742152960396f    // C2*sqrt(3)/2
#define EPS_F 1e-6f

// ws / LDS constant-region layout (bytes). Fragment-major: [tile][lane][4 bf16]
#define W1H_OFF 0        //  4*64*8 = 2048
#define W1L_OFF 2048
#define W2H_OFF 4096     // 16*64*8 = 8192
#define W2L_OFF 12288
#define W3H_OFF 20480    //  4*64*8 = 2048
#define W3L_OFF 22528
#define B1P_OFF 24576    // 64 f32 (b1 + C0*W1[0,:])
#define B2_OFF  24832    // 64 f32
#define B3P_OFF 25088    // 16 f32 (b3 padded with zeros)
#define CONST_BYTES 25152            // = 1572 * 16
#define SH_OFF  25152                // per-wave 3072B: sh rows (48B stride), reused as epilogue [8][64] f32
#define LDS_BYTES (CONST_BYTES + 4*3072)   // 37440

typedef __attribute__((ext_vector_type(4))) short  short4v;   // 4 bf16 (2 VGPR)
typedef __attribute__((ext_vector_type(4))) float  f32x4;
typedef __attribute__((ext_vector_type(4))) unsigned int u32x4;

// ---------- helpers (no inline asm anywhere) ----------
__device__ __forceinline__ f32x4 mfma16(short4v a, short4v b, f32x4 c) {
    // unconditional: if this builtin is absent on gfx950 we WANT a compile error,
    // not a silent hazard-prone asm fallback.
    return __builtin_amdgcn_mfma_f32_16x16x16bf16_1k(a, b, c, 0, 0, 0);
}

__device__ __forceinline__ unsigned short bf16_rne(float v) {
    unsigned u = __float_as_uint(v);
    return (unsigned short)((u + 0x7fffu + ((u >> 16) & 1u)) >> 16);
}
__device__ __forceinline__ float bf16_to_f(unsigned short h) {
    return __uint_as_float(((unsigned)h) << 16);
}

struct fragpair { short4v h, l; };
__device__ __forceinline__ fragpair split4(f32x4 v) {   // f32x4 -> bf16 hi + residual-lo frags
    unsigned short h0 = bf16_rne(v.x), h1 = bf16_rne(v.y),
                   h2 = bf16_rne(v.z), h3 = bf16_rne(v.w);
    unsigned short l0 = bf16_rne(v.x - bf16_to_f(h0));
    unsigned short l1 = bf16_rne(v.y - bf16_to_f(h1));
    unsigned short l2 = bf16_rne(v.z - bf16_to_f(h2));
    unsigned short l3 = bf16_rne(v.w - bf16_to_f(h3));
    fragpair fp;
    fp.h.x = (short)h0; fp.h.y = (short)h1; fp.h.z = (short)h2; fp.h.w = (short)h3;
    fp.l.x = (short)l0; fp.l.y = (short)l1; fp.l.z = (short)l2; fp.l.w = (short)l3;
    return fp;
}

__device__ __forceinline__ float silu_f(float x) {
    return x / (1.0f + __expf(-x));
}
__device__ __forceinline__ f32x4 silu4(f32x4 v) {
    v.x = silu_f(v.x); v.y = silu_f(v.y); v.z = silu_f(v.z); v.w = silu_f(v.w);
    return v;
}

__device__ __forceinline__ void split_bf16_int(float v, unsigned short& h, unsigned short& l) {
    h = bf16_rne(v);
    l = bf16_rne(v - bf16_to_f(h));
}

// ---------- prologue: stage weights into fragment-major split-bf16 layout in ws ----------
__global__ __launch_bounds__(256) void shab_stage(
    const float* __restrict__ w1, const float* __restrict__ b1,
    const float* __restrict__ w2, const float* __restrict__ b2,
    const float* __restrict__ w3, const float* __restrict__ b3,
    unsigned char* __restrict__ ws)
{
    const int gid = blockIdx.x * 256 + threadIdx.x;
    const int gstride = gridDim.x * 256;

    // W2^T frags: A[m][k]: m=ch2=mi*16+(lane&15), k=ch1=ks*16+4*(lane>>4)+i
    for (int idx = gid; idx < 16 * 64 * 4; idx += gstride) {
        const int tile = idx >> 8, lane = (idx >> 2) & 63, i = idx & 3;
        const int mi = tile >> 2, ks = tile & 3;
        const int ch2 = mi * 16 + (lane & 15);
        const int ch1 = ks * 16 + (lane >> 4) * 4 + i;
        unsigned short h, l; split_bf16_int(w2[ch1 * 64 + ch2], h, l);
        ((unsigned short*)(ws + W2H_OFF))[idx] = h;
        ((unsigned short*)(ws + W2L_OFF))[idx] = l;
    }
    // W1^T frags (sh index shifted by 1; k>=8 zero-padded): m=ch, k -> W1[k+1][ch]
    for (int idx = gid; idx < 4 * 64 * 4; idx += gstride) {
        const int tile = idx >> 8, lane = (idx >> 2) & 63, i = idx & 3;
        const int ch = tile * 16 + (lane & 15);
        const int k = (lane >> 4) * 4 + i;
        const float v = (k < 8) ? w1[(k + 1) * 64 + ch] : 0.f;
        unsigned short h, l; split_bf16_int(v, h, l);
        ((unsigned short*)(ws + W1H_OFF))[idx] = h;
        ((unsigned short*)(ws + W1L_OFF))[idx] = l;
    }
    // W3^T frags (heads padded 8->16): m=head, k=ch2 -> W3[ch2][head]
    for (int idx = gid; idx < 4 * 64 * 4; idx += gstride) {
        const int ks = idx >> 8, lane = (idx >> 2) & 63, i = idx & 3;
        const int head = lane & 15;
        const int ch2 = ks * 16 + (lane >> 4) * 4 + i;
        const float v = (head < 8) ? w3[ch2 * 8 + head] : 0.f;
        unsigned short h, l; split_bf16_int(v, h, l);
        ((unsigned short*)(ws + W3H_OFF))[idx] = h;
        ((unsigned short*)(ws + W3L_OFF))[idx] = l;
    }
    if (gid < 64) {
        ((float*)(ws + B1P_OFF))[gid] = b1[gid] + C0_F * w1[gid];  // fold sh[0]=C0 row
        ((float*)(ws + B2_OFF))[gid]  = b2[gid];
    }
    if (gid < 16) ((float*)(ws + B3P_OFF))[gid] = (gid < 8) ? b3[gid] : 0.f;
}

// ---------- main kernel ----------
__global__ __launch_bounds__(256, 2) void shab_mfma(
    const float* __restrict__ coords, const unsigned char* __restrict__ ws,
    float* __restrict__ out)
{
    __shared__ __align__(16) unsigned char lds[LDS_BYTES];
    const int tid = threadIdx.x;
    const int wave = tid >> 6, lane = tid & 63, g = lane >> 4, p = lane & 15;

    // stage constants ws -> LDS (25152B = 1572 x 16B)
    {
        const u32x4* src = (const u32x4*)ws;
        u32x4* dst = (u32x4*)lds;
        #pragma unroll
        for (int k = 0; k < 7; ++k) { int o = tid + k * 256; if (o < 1572) dst[o] = src[o]; }
    }

    const int bid = blockIdx.x;
    const int b = bid >> 12, rem = bid & 4095;
    const int irow = rem >> 2, jt = rem & 3;
    const int j = jt * 256 + wave * 64 + lane;

    // ---- spherical harmonics (per-lane pair: (irow, j)) ----
    const float* cb = coords + (size_t)b * 3 * S_TOK;
    const float xi = cb[irow * 3 + 0], yi = cb[irow * 3 + 1], zi = cb[irow * 3 + 2];
    const float xj = cb[j * 3 + 0],    yj = cb[j * 3 + 1],    zj = cb[j * 3 + 2];
    const float rx = xi - xj, ry = yi - yj, rz = zi - zj;
    const float nrm = sqrtf(rx * rx + ry * ry + rz * rz);
    const float inv1 = 1.0f / (nrm + EPS_F);
    const float ux = rx * inv1, uy = ry * inv1, uz = rz * inv1;
    const float un = sqrtf(ux * ux + uy * uy + uz * uz);
    const float inv2 = 1.0f / fmaxf(un, EPS_F);
    const float x = ux * inv2, y = uy * inv2, z = uz * inv2;

    f32x4 s0, s1;             // sh[1..4], sh[5..8]  (sh[0]=C0 folded into bias1)
    s0.x = C1_F * x; s0.y = C1_F * y; s0.z = C1_F * z; s0.w = C2S3 * x * z;
    s1.x = C2S3 * x * y;
    s1.y = C2_F * (y * y - 0.5f * (x * x + z * z));
    s1.z = C2S3 * y * z;
    s1.w = C2H3 * (z * z - x * x);

    char* shbase = (char*)lds + SH_OFF + wave * 3072;
    *(f32x4*)(shbase + lane * 48)      = s0;   // 48B row stride: full 32-bank spread
    *(f32x4*)(shbase + lane * 48 + 16) = s1;
    __syncthreads();   // covers const-copy AND sh redistribution

    // ---- layer 1: h1^T[ch][pair] = W1^T . sh^T + b1'  (K=16, k>=8 zero in A) ----
    short4v a1h[4], a1l[4]; f32x4 bias1[4];
    #pragma unroll
    for (int mi = 0; mi < 4; ++mi) {
        a1h[mi]  = *(const short4v*)((char*)lds + W1H_OFF + (mi * 64 + lane) * 8);
        a1l[mi]  = *(const short4v*)((char*)lds + W1L_OFF + (mi * 64 + lane) * 8);
        bias1[mi] = *(const f32x4*)((char*)lds + B1P_OFF + (mi * 16 + 4 * g) * 4);
    }
    f32x4 d1[4][4];
    #pragma unroll
    for (int ni = 0; ni < 4; ++ni) {
        // B-frag: lane holds sh[4(g&1)+1 .. +4] of pair ni*16+p (g>=2 lanes: A is zero there)
        f32x4 shv = *(const f32x4*)(shbase + (ni * 16 + p) * 48 + (g & 1) * 16);
        fragpair bf = split4(shv);
        #pragma unroll
        for (int mi = 0; mi < 4; ++mi) {
            f32x4 acc = bias1[mi];
            acc = mfma16(a1h[mi], bf.h, acc);
            acc = mfma16(a1h[mi], bf.l, acc);
            acc = mfma16(a1l[mi], bf.h, acc);
            d1[mi][ni] = acc;
        }
    }

    // ---- silu + split: D1(ks,ni) is exactly layer-2's B-frag(ks,ni) ----
    short4v b2h[4][4], b2l[4][4];
    #pragma unroll
    for (int ks = 0; ks < 4; ++ks)
        #pragma unroll
        for (int ni = 0; ni < 4; ++ni) {
            fragpair fp = split4(silu4(d1[ks][ni]));
            b2h[ks][ni] = fp.h; b2l[ks][ni] = fp.l;
        }

    // ---- layer 2 (+ fused silu/split into layer-3 B-frags) ----
    short4v b3h[4][4], b3l[4][4];
    #pragma unroll
    for (int mi = 0; mi < 4; ++mi) {
        short4v a2h[4], a2l[4];
        #pragma unroll
        for (int ks = 0; ks < 4; ++ks) {
            a2h[ks] = *(const short4v*)((char*)lds + W2H_OFF + ((mi * 4 + ks) * 64 + lane) * 8);
            a2l[ks] = *(const short4v*)((char*)lds + W2L_OFF + ((mi * 4 + ks) * 64 + lane) * 8);
        }
        const f32x4 bias2v = *(const f32x4*)((char*)lds + B2_OFF + (mi * 16 + 4 * g) * 4);
        #pragma unroll
        for (int ni = 0; ni < 4; ++ni) {
            f32x4 acc = bias2v;
            #pragma unroll
            for (int ks = 0; ks < 4; ++ks) {
                acc = mfma16(a2h[ks], b2h[ks][ni], acc);
                acc = mfma16(a2h[ks], b2l[ks][ni], acc);
                acc = mfma16(a2l[ks], b2h[ks][ni], acc);
            }
            fragpair fp = split4(silu4(acc));      // D2(mi,ni) -> B3-frag(ks=mi,ni)
            b3h[mi][ni] = fp.h; b3l[mi][ni] = fp.l;
        }
    }

    // ---- layer 3: out^T[head][pair] (heads padded to 16, rows 8..15 are zero) ----
    short4v a3h[4], a3l[4];
    #pragma unroll
    for (int ks = 0; ks < 4; ++ks) {
        a3h[ks] = *(const short4v*)((char*)lds + W3H_OFF + (ks * 64 + lane) * 8);
        a3l[ks] = *(const short4v*)((char*)lds + W3L_OFF + (ks * 64 + lane) * 8);
    }
    const f32x4 bias3v = *(const f32x4*)((char*)lds + B3P_OFF + 4 * g * 4);
    f32x4 d3[4];
    #pragma unroll
    for (int ni = 0; ni < 4; ++ni) {
        f32x4 acc = bias3v;
        #pragma unroll
        for (int ks = 0; ks < 4; ++ks) {
            acc = mfma16(a3h[ks], b3h[ks][ni], acc);
            acc = mfma16(a3h[ks], b3l[ks][ni], acc);
            acc = mfma16(a3l[ks], b3h[ks][ni], acc);
        }
        d3[ni] = acc;
    }

    // ---- epilogue: transpose via LDS (reuse sh region) for coalesced 256B stores ----
    __syncthreads();   // everyone done reading sh region (it was layer-1 input)
    if (g < 2) {
        #pragma unroll
        for (int ni = 0; ni < 4; ++ni) {
            #pragma unroll
            for (int i2 = 0; i2 < 4; ++i2)
                *(float*)(shbase + (4 * g + i2) * 256 + (ni * 16 + p) * 4) = d3[ni][i2];
        }
    }
    __syncthreads();
    #pragma unroll
    for (int s = 0; s < 8; ++s) {
        const float v = *(const float*)(shbase + s * 256 + lane * 4);
        out[((size_t)(b * 8 + s) << 20) + ((size_t)irow << 10) + j] = v;
    }
}

extern "C" void kernel_launch(void* const* d_in, const int* in_sizes, int n_in,
                              void* d_out, int out_size, void* d_ws, size_t ws_size,
                              hipStream_t stream)
{
    const float* coords = (const float*)d_in[0];
    const float* w1 = (const float*)d_in[1];
    const float* b1 = (const float*)d_in[2];
    const float* w2 = (const float*)d_in[3];
    const float* b2 = (const float*)d_in[4];
    const float* w3 = (const float*)d_in[5];
    const float* b3 = (const float*)d_in[6];
    float* out = (float*)d_out;

    shab_stage<<<16, 256, 0, stream>>>(w1, b1, w2, b2, w3, b3, (unsigned char*)d_ws);

    const int B = in_sizes[0] / (S_TOK * 3);   // = 2
    shab_mfma<<<dim3(B * S_TOK * 4), 256, 0, stream>>>(coords, (const unsigned char*)d_ws, out);
}

// Round 5
// 198.114 us; speedup vs baseline: 2.2224x; 1.3809x over previous
//
#include <hip/hip_runtime.h>
#include <math.h>

// Problem constants (B=2, T=8, N=128 -> S=1024, Hd=64, H=8)
#define S_TOK 1024

// e3nn 'integral' normalization constants
#define C0_F  0.28209479177387814f   // 0.5/sqrt(pi)
#define C1_F  0.4886025119029199f    // sqrt(3/(4pi))
#define C2_F  0.6307831305050401f    // sqrt(5/(4pi))
#define C2S3  1.0925484305920792f    // C2*sqrt(3)
#define C2H3  0.5462742152960396f    // C2*sqrt(3)/2

// ws / LDS constant-region layout (bytes). Fragment-major: [tile][lane][4 bf16]
#define W1H_OFF 0        //  4*64*8 = 2048
#define W1L_OFF 2048
#define W2H_OFF 4096     // 16*64*8 = 8192
#define W2L_OFF 12288
#define W3H_OFF 20480    //  4*64*8 = 2048
#define W3L_OFF 22528
#define B1P_OFF 24576    // 64 f32 (b1 + C0*W1[0,:])
#define B2_OFF  24832    // 64 f32
#define B3P_OFF 25088    // 16 f32 (b3 padded with zeros)
#define CONST_BYTES 25152            // = 1572 * 16
#define SH_OFF  25152                // per-wave 3072B: sh rows (48B stride), reused as epilogue [8][64] f32
#define LDS_BYTES (CONST_BYTES + 4*3072)   // 37440

typedef __attribute__((ext_vector_type(4))) short  short4v;   // 4 bf16 (2 VGPR)
typedef __attribute__((ext_vector_type(4))) float  f32x4;
typedef __attribute__((ext_vector_type(4))) unsigned int u32x4;

// ---------- helpers (no inline asm anywhere) ----------
__device__ __forceinline__ f32x4 mfma16(short4v a, short4v b, f32x4 c) {
    return __builtin_amdgcn_mfma_f32_16x16x16bf16_1k(a, b, c, 0, 0, 0);
}

struct fragpair { short4v h, l; };

// split by TRUNCATION: h = hi16(v), l = hi16(v - h). Residual l captures the
// chop; combined error ~2^-16 relative — far below the 5e-3 threshold.
__device__ __forceinline__ fragpair split4(f32x4 v) {
    const unsigned u0 = __float_as_uint(v.x), u1 = __float_as_uint(v.y),
                   u2 = __float_as_uint(v.z), u3 = __float_as_uint(v.w);
    const float h0f = __uint_as_float(u0 & 0xffff0000u);
    const float h1f = __uint_as_float(u1 & 0xffff0000u);
    const float h2f = __uint_as_float(u2 & 0xffff0000u);
    const float h3f = __uint_as_float(u3 & 0xffff0000u);
    const unsigned r0 = __float_as_uint(v.x - h0f), r1 = __float_as_uint(v.y - h1f),
                   r2 = __float_as_uint(v.z - h2f), r3 = __float_as_uint(v.w - h3f);
    fragpair fp;
    fp.h.x = (short)(u0 >> 16); fp.h.y = (short)(u1 >> 16);
    fp.h.z = (short)(u2 >> 16); fp.h.w = (short)(u3 >> 16);
    fp.l.x = (short)(r0 >> 16); fp.l.y = (short)(r1 >> 16);
    fp.l.z = (short)(r2 >> 16); fp.l.w = (short)(r3 >> 16);
    return fp;
}

__device__ __forceinline__ float silu_f(float x) {
    // x * rcp(1 + exp(-x)); denom >= 1 so raw v_rcp is safe (1 ulp)
    return x * __builtin_amdgcn_rcpf(1.0f + __expf(-x));
}
__device__ __forceinline__ f32x4 silu4(f32x4 v) {
    v.x = silu_f(v.x); v.y = silu_f(v.y); v.z = silu_f(v.z); v.w = silu_f(v.w);
    return v;
}

__device__ __forceinline__ unsigned short bf16_rne(float v) {
    unsigned u = __float_as_uint(v);
    return (unsigned short)((u + 0x7fffu + ((u >> 16) & 1u)) >> 16);
}
__device__ __forceinline__ float bf16_to_f(unsigned short h) {
    return __uint_as_float(((unsigned)h) << 16);
}
__device__ __forceinline__ void split_bf16_int(float v, unsigned short& h, unsigned short& l) {
    h = bf16_rne(v);
    l = bf16_rne(v - bf16_to_f(h));
}

// ---------- prologue: stage weights into fragment-major split-bf16 layout in ws ----------
__global__ __launch_bounds__(256) void shab_stage(
    const float* __restrict__ w1, const float* __restrict__ b1,
    const float* __restrict__ w2, const float* __restrict__ b2,
    const float* __restrict__ w3, const float* __restrict__ b3,
    unsigned char* __restrict__ ws)
{
    const int gid = blockIdx.x * 256 + threadIdx.x;
    const int gstride = gridDim.x * 256;

    // W2^T frags: A[m][k]: m=ch2=mi*16+(lane&15), k=ch1=ks*16+4*(lane>>4)+i
    for (int idx = gid; idx < 16 * 64 * 4; idx += gstride) {
        const int tile = idx >> 8, lane = (idx >> 2) & 63, i = idx & 3;
        const int mi = tile >> 2, ks = tile & 3;
        const int ch2 = mi * 16 + (lane & 15);
        const int ch1 = ks * 16 + (lane >> 4) * 4 + i;
        unsigned short h, l; split_bf16_int(w2[ch1 * 64 + ch2], h, l);
        ((unsigned short*)(ws + W2H_OFF))[idx] = h;
        ((unsigned short*)(ws + W2L_OFF))[idx] = l;
    }
    // W1^T frags (sh index shifted by 1; k>=8 zero-padded): m=ch, k -> W1[k+1][ch]
    for (int idx = gid; idx < 4 * 64 * 4; idx += gstride) {
        const int tile = idx >> 8, lane = (idx >> 2) & 63, i = idx & 3;
        const int ch = tile * 16 + (lane & 15);
        const int k = (lane >> 4) * 4 + i;
        const float v = (k < 8) ? w1[(k + 1) * 64 + ch] : 0.f;
        unsigned short h, l; split_bf16_int(v, h, l);
        ((unsigned short*)(ws + W1H_OFF))[idx] = h;
        ((unsigned short*)(ws + W1L_OFF))[idx] = l;
    }
    // W3^T frags (heads padded 8->16): m=head, k=ch2 -> W3[ch2][head]
    for (int idx = gid; idx < 4 * 64 * 4; idx += gstride) {
        const int ks = idx >> 8, lane = (idx >> 2) & 63, i = idx & 3;
        const int head = lane & 15;
        const int ch2 = ks * 16 + (lane >> 4) * 4 + i;
        const float v = (head < 8) ? w3[ch2 * 8 + head] : 0.f;
        unsigned short h, l; split_bf16_int(v, h, l);
        ((unsigned short*)(ws + W3H_OFF))[idx] = h;
        ((unsigned short*)(ws + W3L_OFF))[idx] = l;
    }
    if (gid < 64) {
        ((float*)(ws + B1P_OFF))[gid] = b1[gid] + C0_F * w1[gid];  // fold sh[0]=C0 row
        ((float*)(ws + B2_OFF))[gid]  = b2[gid];
    }
    if (gid < 16) ((float*)(ws + B3P_OFF))[gid] = (gid < 8) ? b3[gid] : 0.f;
}

// ---------- main kernel ----------
__global__ __launch_bounds__(256, 4) void shab_mfma(
    const float* __restrict__ coords, const unsigned char* __restrict__ ws,
    float* __restrict__ out)
{
    __shared__ __align__(16) unsigned char lds[LDS_BYTES];
    const int tid = threadIdx.x;
    const int wave = tid >> 6, lane = tid & 63, g = lane >> 4, p = lane & 15;

    // stage constants ws -> LDS (25152B = 1572 x 16B)
    {
        const u32x4* src = (const u32x4*)ws;
        u32x4* dst = (u32x4*)lds;
        #pragma unroll
        for (int k = 0; k < 7; ++k) { int o = tid + k * 256; if (o < 1572) dst[o] = src[o]; }
    }

    const int bid = blockIdx.x;
    const int b = bid >> 12, rem = bid & 4095;
    const int irow = rem >> 2, jt = rem & 3;
    const int j = jt * 256 + wave * 64 + lane;

    // ---- spherical harmonics (per-lane pair: (irow, j)) ----
    // Reference's two-step normalize == rel/||rel|| (zero stays zero):
    // single rsqrt with a zero guard is equivalent to ~1e-6.
    const float* cb = coords + (size_t)b * 3 * S_TOK;
    const float xi = cb[irow * 3 + 0], yi = cb[irow * 3 + 1], zi = cb[irow * 3 + 2];
    const float xj = cb[j * 3 + 0],    yj = cb[j * 3 + 1],    zj = cb[j * 3 + 2];
    const float rx = xi - xj, ry = yi - yj, rz = zi - zj;
    const float n2 = rx * rx + ry * ry + rz * rz;
    const float inv = (n2 > 0.f) ? __builtin_amdgcn_rsqf(n2) : 0.f;
    const float x = rx * inv, y = ry * inv, z = rz * inv;

    f32x4 s0, s1;             // sh[1..4], sh[5..8]  (sh[0]=C0 folded into bias1)
    s0.x = C1_F * x; s0.y = C1_F * y; s0.z = C1_F * z; s0.w = C2S3 * x * z;
    s1.x = C2S3 * x * y;
    s1.y = C2_F * (y * y - 0.5f * (x * x + z * z));
    s1.z = C2S3 * y * z;
    s1.w = C2H3 * (z * z - x * x);

    char* shbase = (char*)lds + SH_OFF + wave * 3072;
    *(f32x4*)(shbase + lane * 48)      = s0;   // 48B row stride: full 32-bank spread
    *(f32x4*)(shbase + lane * 48 + 16) = s1;
    __syncthreads();   // covers const-copy AND sh redistribution

    // ---- layer 1: h1^T[ch][pair] = W1^T . sh^T + b1'  (K=16, k>=8 zero in A) ----
    short4v a1h[4], a1l[4]; f32x4 bias1[4];
    #pragma unroll
    for (int mi = 0; mi < 4; ++mi) {
        a1h[mi]  = *(const short4v*)((char*)lds + W1H_OFF + (mi * 64 + lane) * 8);
        a1l[mi]  = *(const short4v*)((char*)lds + W1L_OFF + (mi * 64 + lane) * 8);
        bias1[mi] = *(const f32x4*)((char*)lds + B1P_OFF + (mi * 16 + 4 * g) * 4);
    }
    f32x4 d1[4][4];
    #pragma unroll
    for (int ni = 0; ni < 4; ++ni) {
        // B-frag: lane holds sh[4(g&1)+1 .. +4] of pair ni*16+p (g>=2 lanes: A is zero there)
        f32x4 shv = *(const f32x4*)(shbase + (ni * 16 + p) * 48 + (g & 1) * 16);
        fragpair bf = split4(shv);
        #pragma unroll
        for (int mi = 0; mi < 4; ++mi) {
            f32x4 acc = bias1[mi];
            acc = mfma16(a1h[mi], bf.h, acc);
            acc = mfma16(a1h[mi], bf.l, acc);
            acc = mfma16(a1l[mi], bf.h, acc);
            d1[mi][ni] = acc;
        }
    }

    // ---- silu + split: D1(ks,ni) is exactly layer-2's B-frag(ks,ni) ----
    short4v b2h[4][4], b2l[4][4];
    #pragma unroll
    for (int ks = 0; ks < 4; ++ks)
        #pragma unroll
        for (int ni = 0; ni < 4; ++ni) {
            fragpair fp = split4(silu4(d1[ks][ni]));
            b2h[ks][ni] = fp.h; b2l[ks][ni] = fp.l;
        }

    // ---- layer 2 (+ fused silu/split into layer-3 B-frags) ----
    short4v b3h[4][4], b3l[4][4];
    #pragma unroll
    for (int mi = 0; mi < 4; ++mi) {
        short4v a2h[4], a2l[4];
        #pragma unroll
        for (int ks = 0; ks < 4; ++ks) {
            a2h[ks] = *(const short4v*)((char*)lds + W2H_OFF + ((mi * 4 + ks) * 64 + lane) * 8);
            a2l[ks] = *(const short4v*)((char*)lds + W2L_OFF + ((mi * 4 + ks) * 64 + lane) * 8);
        }
        const f32x4 bias2v = *(const f32x4*)((char*)lds + B2_OFF + (mi * 16 + 4 * g) * 4);
        #pragma unroll
        for (int ni = 0; ni < 4; ++ni) {
            f32x4 acc = bias2v;
            #pragma unroll
            for (int ks = 0; ks < 4; ++ks) {
                acc = mfma16(a2h[ks], b2h[ks][ni], acc);
                acc = mfma16(a2h[ks], b2l[ks][ni], acc);
                acc = mfma16(a2l[ks], b2h[ks][ni], acc);
            }
            fragpair fp = split4(silu4(acc));      // D2(mi,ni) -> B3-frag(ks=mi,ni)
            b3h[mi][ni] = fp.h; b3l[mi][ni] = fp.l;
        }
    }

    // ---- layer 3: out^T[head][pair] (heads padded to 16, rows 8..15 are zero) ----
    short4v a3h[4], a3l[4];
    #pragma unroll
    for (int ks = 0; ks < 4; ++ks) {
        a3h[ks] = *(const short4v*)((char*)lds + W3H_OFF + (ks * 64 + lane) * 8);
        a3l[ks] = *(const short4v*)((char*)lds + W3L_OFF + (ks * 64 + lane) * 8);
    }
    const f32x4 bias3v = *(const f32x4*)((char*)lds + B3P_OFF + 4 * g * 4);
    f32x4 d3[4];
    #pragma unroll
    for (int ni = 0; ni < 4; ++ni) {
        f32x4 acc = bias3v;
        #pragma unroll
        for (int ks = 0; ks < 4; ++ks) {
            acc = mfma16(a3h[ks], b3h[ks][ni], acc);
            acc = mfma16(a3h[ks], b3l[ks][ni], acc);
            acc = mfma16(a3l[ks], b3h[ks][ni], acc);
        }
        d3[ni] = acc;
    }

    // ---- epilogue: transpose via LDS (reuse sh region) for coalesced 256B stores ----
    __syncthreads();   // everyone done reading sh region (it was layer-1 input)
    if (g < 2) {
        #pragma unroll
        for (int ni = 0; ni < 4; ++ni) {
            #pragma unroll
            for (int i2 = 0; i2 < 4; ++i2)
                *(float*)(shbase + (4 * g + i2) * 256 + (ni * 16 + p) * 4) = d3[ni][i2];
        }
    }
    __syncthreads();
    #pragma unroll
    for (int s = 0; s < 8; ++s) {
        const float v = *(const float*)(shbase + s * 256 + lane * 4);
        out[((size_t)(b * 8 + s) << 20) + ((size_t)irow << 10) + j] = v;
    }
}

extern "C" void kernel_launch(void* const* d_in, const int* in_sizes, int n_in,
                              void* d_out, int out_size, void* d_ws, size_t ws_size,
                              hipStream_t stream)
{
    const float* coords = (const float*)d_in[0];
    const float* w1 = (const float*)d_in[1];
    const float* b1 = (const float*)d_in[2];
    const float* w2 = (const float*)d_in[3];
    const float* b2 = (const float*)d_in[4];
    const float* w3 = (const float*)d_in[5];
    const float* b3 = (const float*)d_in[6];
    float* out = (float*)d_out;

    shab_stage<<<16, 256, 0, stream>>>(w1, b1, w2, b2, w3, b3, (unsigned char*)d_ws);

    const int B = in_sizes[0] / (S_TOK * 3);   // = 2
    shab_mfma<<<dim3(B * S_TOK * 4), 256, 0, stream>>>(coords, (const unsigned char*)d_ws, out);
}

// Round 6
// 147.124 us; speedup vs baseline: 2.9927x; 1.3466x over previous
//
#include <hip/hip_runtime.h>
#include <math.h>

// Problem constants (B=2, T=8, N=128 -> S=1024, Hd=64, H=8)
#define S_TOK 1024

// e3nn 'integral' normalization constants
#define C0_F  0.28209479177387814f   // 0.5/sqrt(pi)
#define C1_F  0.4886025119029199f    // sqrt(3/(4pi))
#define C2_F  0.6307831305050401f    // sqrt(5/(4pi))
#define C2S3  1.0925484305920792f    // C2*sqrt(3)
#define C2H3  0.5462742152960396f    // C2*sqrt(3)/2

// ws / LDS constant-region layout (bytes). Fragment-major fp16: [tile][lane][4 f16]
#define W1_OFF  0        // 4*64*8  = 2048
#define W2_OFF  2048     // 16*64*8 = 8192
#define W3_OFF  10240    // 4*64*8  = 2048
#define B1P_OFF 12288    // 64 f32 (b1 + C0*W1[0,:])
#define B2_OFF  12544    // 64 f32
#define B3P_OFF 12800    // 16 f32 (b3 padded with zeros)
#define CONST_BYTES 12864            // = 804 * 16
#define SH_OFF  12864                // per-wave 3072B: sh rows (48B stride), reused as epilogue [8][64] f32
#define LDS_BYTES (CONST_BYTES + 4*3072)   // 25152

typedef __attribute__((ext_vector_type(2))) _Float16 half2v;
typedef __attribute__((ext_vector_type(4))) _Float16 half4v;   // 4 f16 (2 VGPR)
typedef __attribute__((ext_vector_type(2))) unsigned int uint2v;
typedef __attribute__((ext_vector_type(4))) float  f32x4;
typedef __attribute__((ext_vector_type(4))) unsigned int u32x4;

// ---------- helpers ----------
__device__ __forceinline__ f32x4 mfma16h(half4v a, half4v b, f32x4 c) {
    return __builtin_amdgcn_mfma_f32_16x16x16f16(a, b, c, 0, 0, 0);
}

// f32x4 -> 4 packed fp16 via v_cvt_pkrtz_f16_f32 (2 ops total)
__device__ __forceinline__ half4v cvt4(f32x4 v) {
    uint2v t;
    t.x = __builtin_bit_cast(unsigned, __builtin_amdgcn_cvt_pkrtz(v.x, v.y));
    t.y = __builtin_bit_cast(unsigned, __builtin_amdgcn_cvt_pkrtz(v.z, v.w));
    return __builtin_bit_cast(half4v, t);
}

__device__ __forceinline__ float silu_f(float x) {
    // x * rcp(1 + exp(-x)); denom >= 1 so raw v_rcp is safe (1 ulp)
    return x * __builtin_amdgcn_rcpf(1.0f + __expf(-x));
}
__device__ __forceinline__ f32x4 silu4(f32x4 v) {
    v.x = silu_f(v.x); v.y = silu_f(v.y); v.z = silu_f(v.z); v.w = silu_f(v.w);
    return v;
}

// ---------- prologue: stage weights into fragment-major fp16 layout in ws ----------
__global__ __launch_bounds__(256) void shab_stage(
    const float* __restrict__ w1, const float* __restrict__ b1,
    const float* __restrict__ w2, const float* __restrict__ b2,
    const float* __restrict__ w3, const float* __restrict__ b3,
    unsigned char* __restrict__ ws)
{
    const int gid = blockIdx.x * 256 + threadIdx.x;
    const int gstride = gridDim.x * 256;

    // W2^T frags: A[m][k]: m=ch2=mi*16+(lane&15), k=ch1=ks*16+4*(lane>>4)+i
    for (int idx = gid; idx < 16 * 64 * 4; idx += gstride) {
        const int tile = idx >> 8, lane = (idx >> 2) & 63, i = idx & 3;
        const int mi = tile >> 2, ks = tile & 3;
        const int ch2 = mi * 16 + (lane & 15);
        const int ch1 = ks * 16 + (lane >> 4) * 4 + i;
        ((_Float16*)(ws + W2_OFF))[idx] = (_Float16)w2[ch1 * 64 + ch2];   // RNE
    }
    // W1^T frags (sh index shifted by 1; k>=8 zero-padded): m=ch, k -> W1[k+1][ch]
    for (int idx = gid; idx < 4 * 64 * 4; idx += gstride) {
        const int tile = idx >> 8, lane = (idx >> 2) & 63, i = idx & 3;
        const int ch = tile * 16 + (lane & 15);
        const int k = (lane >> 4) * 4 + i;
        const float v = (k < 8) ? w1[(k + 1) * 64 + ch] : 0.f;
        ((_Float16*)(ws + W1_OFF))[idx] = (_Float16)v;
    }
    // W3^T frags (heads padded 8->16): m=head, k=ch2 -> W3[ch2][head]
    for (int idx = gid; idx < 4 * 64 * 4; idx += gstride) {
        const int ks = idx >> 8, lane = (idx >> 2) & 63, i = idx & 3;
        const int head = lane & 15;
        const int ch2 = ks * 16 + (lane >> 4) * 4 + i;
        const float v = (head < 8) ? w3[ch2 * 8 + head] : 0.f;
        ((_Float16*)(ws + W3_OFF))[idx] = (_Float16)v;
    }
    if (gid < 64) {
        ((float*)(ws + B1P_OFF))[gid] = b1[gid] + C0_F * w1[gid];  // fold sh[0]=C0 row
        ((float*)(ws + B2_OFF))[gid]  = b2[gid];
    }
    if (gid < 16) ((float*)(ws + B3P_OFF))[gid] = (gid < 8) ? b3[gid] : 0.f;
}

// ---------- main kernel ----------
__global__ __launch_bounds__(256, 6) void shab_mfma(
    const float* __restrict__ coords, const unsigned char* __restrict__ ws,
    float* __restrict__ out)
{
    __shared__ __align__(16) unsigned char lds[LDS_BYTES];
    const int tid = threadIdx.x;
    const int wave = tid >> 6, lane = tid & 63, g = lane >> 4, p = lane & 15;

    // stage constants ws -> LDS (12864B = 804 x 16B)
    {
        const u32x4* src = (const u32x4*)ws;
        u32x4* dst = (u32x4*)lds;
        #pragma unroll
        for (int k = 0; k < 4; ++k) { int o = tid + k * 256; if (o < 804) dst[o] = src[o]; }
    }

    const int bid = blockIdx.x;
    const int b = bid >> 12, rem = bid & 4095;
    const int irow = rem >> 2, jt = rem & 3;
    const int j = jt * 256 + wave * 64 + lane;

    // ---- spherical harmonics (per-lane pair: (irow, j)) ----
    // Reference's two-step normalize == rel/||rel|| (zero stays zero).
    const float* cb = coords + (size_t)b * 3 * S_TOK;
    const float xi = cb[irow * 3 + 0], yi = cb[irow * 3 + 1], zi = cb[irow * 3 + 2];
    const float xj = cb[j * 3 + 0],    yj = cb[j * 3 + 1],    zj = cb[j * 3 + 2];
    const float rx = xi - xj, ry = yi - yj, rz = zi - zj;
    const float n2 = rx * rx + ry * ry + rz * rz;
    const float inv = (n2 > 0.f) ? __builtin_amdgcn_rsqf(n2) : 0.f;
    const float x = rx * inv, y = ry * inv, z = rz * inv;

    f32x4 s0, s1;             // sh[1..4], sh[5..8]  (sh[0]=C0 folded into bias1)
    s0.x = C1_F * x; s0.y = C1_F * y; s0.z = C1_F * z; s0.w = C2S3 * x * z;
    s1.x = C2S3 * x * y;
    s1.y = C2_F * (y * y - 0.5f * (x * x + z * z));
    s1.z = C2S3 * y * z;
    s1.w = C2H3 * (z * z - x * x);

    char* shbase = (char*)lds + SH_OFF + wave * 3072;
    *(f32x4*)(shbase + lane * 48)      = s0;   // 48B row stride: full 32-bank spread
    *(f32x4*)(shbase + lane * 48 + 16) = s1;
    __syncthreads();   // covers const-copy AND sh redistribution

    // ---- layer 1: h1^T[ch][pair] = W1^T . sh^T + b1'  (K=16, k>=8 zero in A) ----
    half4v a1[4]; f32x4 bias1[4];
    #pragma unroll
    for (int mi = 0; mi < 4; ++mi) {
        a1[mi]    = *(const half4v*)((char*)lds + W1_OFF + (mi * 64 + lane) * 8);
        bias1[mi] = *(const f32x4*)((char*)lds + B1P_OFF + (mi * 16 + 4 * g) * 4);
    }
    f32x4 d1[4][4];
    #pragma unroll
    for (int ni = 0; ni < 4; ++ni) {
        // B-frag: lane holds sh[4(g&1)+1 .. +4] of pair ni*16+p (g>=2 lanes: A is zero there)
        f32x4 shv = *(const f32x4*)(shbase + (ni * 16 + p) * 48 + (g & 1) * 16);
        half4v bf = cvt4(shv);
        #pragma unroll
        for (int mi = 0; mi < 4; ++mi)
            d1[mi][ni] = mfma16h(a1[mi], bf, bias1[mi]);
    }

    // ---- silu + pack: D1(ks,ni) is exactly layer-2's B-frag(ks,ni) ----
    half4v b2f[4][4];
    #pragma unroll
    for (int ks = 0; ks < 4; ++ks)
        #pragma unroll
        for (int ni = 0; ni < 4; ++ni)
            b2f[ks][ni] = cvt4(silu4(d1[ks][ni]));

    // ---- layer 2 (+ fused silu/pack into layer-3 B-frags) ----
    half4v b3f[4][4];
    #pragma unroll
    for (int mi = 0; mi < 4; ++mi) {
        half4v a2[4];
        #pragma unroll
        for (int ks = 0; ks < 4; ++ks)
            a2[ks] = *(const half4v*)((char*)lds + W2_OFF + ((mi * 4 + ks) * 64 + lane) * 8);
        const f32x4 bias2v = *(const f32x4*)((char*)lds + B2_OFF + (mi * 16 + 4 * g) * 4);
        #pragma unroll
        for (int ni = 0; ni < 4; ++ni) {
            f32x4 acc = bias2v;
            #pragma unroll
            for (int ks = 0; ks < 4; ++ks)
                acc = mfma16h(a2[ks], b2f[ks][ni], acc);
            b3f[mi][ni] = cvt4(silu4(acc));        // D2(mi,ni) -> B3-frag(ks=mi,ni)
        }
    }

    // ---- layer 3: out^T[head][pair] (heads padded to 16, rows 8..15 are zero) ----
    half4v a3[4];
    #pragma unroll
    for (int ks = 0; ks < 4; ++ks)
        a3[ks] = *(const half4v*)((char*)lds + W3_OFF + (ks * 64 + lane) * 8);
    const f32x4 bias3v = *(const f32x4*)((char*)lds + B3P_OFF + 4 * g * 4);
    f32x4 d3[4];
    #pragma unroll
    for (int ni = 0; ni < 4; ++ni) {
        f32x4 acc = bias3v;
        #pragma unroll
        for (int ks = 0; ks < 4; ++ks)
            acc = mfma16h(a3[ks], b3f[ks][ni], acc);
        d3[ni] = acc;
    }

    // ---- epilogue: transpose via LDS (reuse sh region) for coalesced 256B stores ----
    __syncthreads();   // everyone done reading sh region (it was layer-1 input)
    if (g < 2) {
        #pragma unroll
        for (int ni = 0; ni < 4; ++ni) {
            #pragma unroll
            for (int i2 = 0; i2 < 4; ++i2)
                *(float*)(shbase + (4 * g + i2) * 256 + (ni * 16 + p) * 4) = d3[ni][i2];
        }
    }
    __syncthreads();
    #pragma unroll
    for (int s = 0; s < 8; ++s) {
        const float v = *(const float*)(shbase + s * 256 + lane * 4);
        out[((size_t)(b * 8 + s) << 20) + ((size_t)irow << 10) + j] = v;
    }
}

extern "C" void kernel_launch(void* const* d_in, const int* in_sizes, int n_in,
                              void* d_out, int out_size, void* d_ws, size_t ws_size,
                              hipStream_t stream)
{
    const float* coords = (const float*)d_in[0];
    const float* w1 = (const float*)d_in[1];
    const float* b1 = (const float*)d_in[2];
    const float* w2 = (const float*)d_in[3];
    const float* b2 = (const float*)d_in[4];
    const float* w3 = (const float*)d_in[5];
    const float* b3 = (const float*)d_in[6];
    float* out = (float*)d_out;

    shab_stage<<<16, 256, 0, stream>>>(w1, b1, w2, b2, w3, b3, (unsigned char*)d_ws);

    const int B = in_sizes[0] / (S_TOK * 3);   // = 2
    shab_mfma<<<dim3(B * S_TOK * 4), 256, 0, stream>>>(coords, (const unsigned char*)d_ws, out);
}

// Round 7
// 146.122 us; speedup vs baseline: 3.0132x; 1.0069x over previous
//
#include <hip/hip_runtime.h>
#include <math.h>

// Problem constants (B=2, T=8, N=128 -> S=1024, Hd=64, H=8)
#define S_TOK 1024

// e3nn 'integral' normalization constants
#define C0_F  0.28209479177387814f   // 0.5/sqrt(pi)
#define C1_F  0.4886025119029199f    // sqrt(3/(4pi))
#define C2_F  0.6307831305050401f    // sqrt(5/(4pi))
#define C2S3  1.0925484305920792f    // C2*sqrt(3)
#define C2H3  0.5462742152960396f    // C2*sqrt(3)/2

// ws / LDS constant-region layout (bytes). Fragment-major fp16: [tile][lane][4 f16]
#define W1_OFF  0        // 4*64*8  = 2048
#define W2_OFF  2048     // 16*64*8 = 8192
#define W3_OFF  10240    // 4*64*8  = 2048
#define B1P_OFF 12288    // 64 f32 (b1 + C0*W1[0,:])
#define B2_OFF  12544    // 64 f32
#define B3P_OFF 12800    // 16 f32 (b3 padded with zeros)
#define CONST_BYTES 12864            // = 804 * 16
#define SH_OFF  12864                // per-wave 3072B: sh rows (48B stride), reused as epilogue [8][64] f32
#define LDS_BYTES (CONST_BYTES + 4*3072)   // 25152

typedef __attribute__((ext_vector_type(4))) _Float16 half4v;   // 4 f16 (2 VGPR)
typedef __attribute__((ext_vector_type(2))) unsigned int uint2v;
typedef __attribute__((ext_vector_type(4))) float  f32x4;
typedef __attribute__((ext_vector_type(4))) unsigned int u32x4;

// ---------- helpers ----------
__device__ __forceinline__ f32x4 mfma16h(half4v a, half4v b, f32x4 c) {
    return __builtin_amdgcn_mfma_f32_16x16x16f16(a, b, c, 0, 0, 0);
}

// f32x4 -> 4 packed fp16 via v_cvt_pkrtz_f16_f32 (2 ops total)
__device__ __forceinline__ half4v cvt4(f32x4 v) {
    uint2v t;
    t.x = __builtin_bit_cast(unsigned, __builtin_amdgcn_cvt_pkrtz(v.x, v.y));
    t.y = __builtin_bit_cast(unsigned, __builtin_amdgcn_cvt_pkrtz(v.z, v.w));
    return __builtin_bit_cast(half4v, t);
}

__device__ __forceinline__ float silu_f(float x) {
    // x * rcp(1 + exp(-x)); denom >= 1 so raw v_rcp is safe (1 ulp)
    return x * __builtin_amdgcn_rcpf(1.0f + __expf(-x));
}
__device__ __forceinline__ f32x4 silu4(f32x4 v) {
    v.x = silu_f(v.x); v.y = silu_f(v.y); v.z = silu_f(v.z); v.w = silu_f(v.w);
    return v;
}

// ---------- prologue: stage weights into fragment-major fp16 layout in ws ----------
__global__ __launch_bounds__(256) void shab_stage(
    const float* __restrict__ w1, const float* __restrict__ b1,
    const float* __restrict__ w2, const float* __restrict__ b2,
    const float* __restrict__ w3, const float* __restrict__ b3,
    unsigned char* __restrict__ ws)
{
    const int gid = blockIdx.x * 256 + threadIdx.x;
    const int gstride = gridDim.x * 256;

    // W2^T frags: A[m][k]: m=ch2=mi*16+(lane&15), k=ch1=ks*16+4*(lane>>4)+i
    for (int idx = gid; idx < 16 * 64 * 4; idx += gstride) {
        const int tile = idx >> 8, lane = (idx >> 2) & 63, i = idx & 3;
        const int mi = tile >> 2, ks = tile & 3;
        const int ch2 = mi * 16 + (lane & 15);
        const int ch1 = ks * 16 + (lane >> 4) * 4 + i;
        ((_Float16*)(ws + W2_OFF))[idx] = (_Float16)w2[ch1 * 64 + ch2];   // RNE
    }
    // W1^T frags (sh index shifted by 1; k>=8 zero-padded): m=ch, k -> W1[k+1][ch]
    for (int idx = gid; idx < 4 * 64 * 4; idx += gstride) {
        const int tile = idx >> 8, lane = (idx >> 2) & 63, i = idx & 3;
        const int ch = tile * 16 + (lane & 15);
        const int k = (lane >> 4) * 4 + i;
        const float v = (k < 8) ? w1[(k + 1) * 64 + ch] : 0.f;
        ((_Float16*)(ws + W1_OFF))[idx] = (_Float16)v;
    }
    // W3^T frags (heads padded 8->16): m=head, k=ch2 -> W3[ch2][head]
    for (int idx = gid; idx < 4 * 64 * 4; idx += gstride) {
        const int ks = idx >> 8, lane = (idx >> 2) & 63, i = idx & 3;
        const int head = lane & 15;
        const int ch2 = ks * 16 + (lane >> 4) * 4 + i;
        const float v = (head < 8) ? w3[ch2 * 8 + head] : 0.f;
        ((_Float16*)(ws + W3_OFF))[idx] = (_Float16)v;
    }
    if (gid < 64) {
        ((float*)(ws + B1P_OFF))[gid] = b1[gid] + C0_F * w1[gid];  // fold sh[0]=C0 row
        ((float*)(ws + B2_OFF))[gid]  = b2[gid];
    }
    if (gid < 16) ((float*)(ws + B3P_OFF))[gid] = (gid < 8) ? b3[gid] : 0.f;
}

// ---------- main kernel ----------
__global__ __launch_bounds__(256, 5) void shab_mfma(
    const float* __restrict__ coords, const unsigned char* __restrict__ ws,
    float* __restrict__ out)
{
    __shared__ __align__(16) unsigned char lds[LDS_BYTES];
    const int tid = threadIdx.x;
    const int wave = tid >> 6, lane = tid & 63, g = lane >> 4, p = lane & 15;

    // stage constants ws -> LDS (12864B = 804 x 16B)
    {
        const u32x4* src = (const u32x4*)ws;
        u32x4* dst = (u32x4*)lds;
        #pragma unroll
        for (int k = 0; k < 4; ++k) { int o = tid + k * 256; if (o < 804) dst[o] = src[o]; }
    }

    const int bid = blockIdx.x;
    const int b = bid >> 12, rem = bid & 4095;
    const int irow = rem >> 2, jt = rem & 3;
    const int j = jt * 256 + wave * 64 + lane;

    // ---- spherical harmonics (per-lane pair: (irow, j)) ----
    // Reference's two-step normalize == rel/||rel|| (zero stays zero).
    const float* cb = coords + (size_t)b * 3 * S_TOK;
    const float xi = cb[irow * 3 + 0], yi = cb[irow * 3 + 1], zi = cb[irow * 3 + 2];
    const float xj = cb[j * 3 + 0],    yj = cb[j * 3 + 1],    zj = cb[j * 3 + 2];
    const float rx = xi - xj, ry = yi - yj, rz = zi - zj;
    const float n2 = rx * rx + ry * ry + rz * rz;
    const float inv = (n2 > 0.f) ? __builtin_amdgcn_rsqf(n2) : 0.f;
    const float x = rx * inv, y = ry * inv, z = rz * inv;

    f32x4 s0, s1;             // sh[1..4], sh[5..8]  (sh[0]=C0 folded into bias1)
    s0.x = C1_F * x; s0.y = C1_F * y; s0.z = C1_F * z; s0.w = C2S3 * x * z;
    s1.x = C2S3 * x * y;
    s1.y = C2_F * (y * y - 0.5f * (x * x + z * z));
    s1.z = C2S3 * y * z;
    s1.w = C2H3 * (z * z - x * x);

    char* shbase = (char*)lds + SH_OFF + wave * 3072;
    *(f32x4*)(shbase + lane * 48)      = s0;   // 48B row stride: full 32-bank spread
    *(f32x4*)(shbase + lane * 48 + 16) = s1;
    __syncthreads();   // covers const-copy AND sh redistribution

    // ---- layer 1 (fused silu+pack: d1 never materializes as an array) ----
    // h1^T[ch][pair] = W1^T . sh^T + b1'  (K=16, k>=8 zero in A)
    half4v a1[4]; f32x4 bias1[4];
    #pragma unroll
    for (int mi = 0; mi < 4; ++mi) {
        a1[mi]    = *(const half4v*)((char*)lds + W1_OFF + (mi * 64 + lane) * 8);
        bias1[mi] = *(const f32x4*)((char*)lds + B1P_OFF + (mi * 16 + 4 * g) * 4);
    }
    half4v b2f[4][4];          // layer-2 B-frags (only 32 VGPRs live)
    #pragma unroll
    for (int ni = 0; ni < 4; ++ni) {
        // B-frag: lane holds sh[4(g&1)+1 .. +4] of pair ni*16+p (g>=2 lanes: A is zero there)
        f32x4 shv = *(const f32x4*)(shbase + (ni * 16 + p) * 48 + (g & 1) * 16);
        half4v bf = cvt4(shv);
        #pragma unroll
        for (int mi = 0; mi < 4; ++mi) {
            f32x4 acc = mfma16h(a1[mi], bf, bias1[mi]);
            b2f[mi][ni] = cvt4(silu4(acc));        // D1(mi,ni) -> B2-frag(ks=mi,ni)
        }
    }

    // ---- layer 2 with layer-3 accumulation fused into the mi loop ----
    // (b3f k-slice dies immediately; acc3 order = ks ascending, bit-identical)
    half4v a3[4];
    #pragma unroll
    for (int ks = 0; ks < 4; ++ks)
        a3[ks] = *(const half4v*)((char*)lds + W3_OFF + (ks * 64 + lane) * 8);
    const f32x4 bias3v = *(const f32x4*)((char*)lds + B3P_OFF + 4 * g * 4);
    f32x4 acc3[4];
    #pragma unroll
    for (int ni = 0; ni < 4; ++ni) acc3[ni] = bias3v;

    #pragma unroll
    for (int mi = 0; mi < 4; ++mi) {
        half4v a2[4];
        #pragma unroll
        for (int ks = 0; ks < 4; ++ks)
            a2[ks] = *(const half4v*)((char*)lds + W2_OFF + ((mi * 4 + ks) * 64 + lane) * 8);
        const f32x4 bias2v = *(const f32x4*)((char*)lds + B2_OFF + (mi * 16 + 4 * g) * 4);
        #pragma unroll
        for (int ni = 0; ni < 4; ++ni) {
            f32x4 acc = bias2v;
            #pragma unroll
            for (int ks = 0; ks < 4; ++ks)
                acc = mfma16h(a2[ks], b2f[ks][ni], acc);
            half4v b3 = cvt4(silu4(acc));          // D2(mi,ni) -> B3-frag(ks=mi,ni)
            acc3[ni] = mfma16h(a3[mi], b3, acc3[ni]);
        }
    }

    // ---- epilogue: transpose via LDS (reuse sh region) for coalesced 256B stores ----
    __syncthreads();   // everyone done reading sh region (it was layer-1 input)
    if (g < 2) {
        #pragma unroll
        for (int ni = 0; ni < 4; ++ni) {
            #pragma unroll
            for (int i2 = 0; i2 < 4; ++i2)
                *(float*)(shbase + (4 * g + i2) * 256 + (ni * 16 + p) * 4) = acc3[ni][i2];
        }
    }
    __syncthreads();
    #pragma unroll
    for (int s = 0; s < 8; ++s) {
        const float v = *(const float*)(shbase + s * 256 + lane * 4);
        out[((size_t)(b * 8 + s) << 20) + ((size_t)irow << 10) + j] = v;
    }
}

extern "C" void kernel_launch(void* const* d_in, const int* in_sizes, int n_in,
                              void* d_out, int out_size, void* d_ws, size_t ws_size,
                              hipStream_t stream)
{
    const float* coords = (const float*)d_in[0];
    const float* w1 = (const float*)d_in[1];
    const float* b1 = (const float*)d_in[2];
    const float* w2 = (const float*)d_in[3];
    const float* b2 = (const float*)d_in[4];
    const float* w3 = (const float*)d_in[5];
    const float* b3 = (const float*)d_in[6];
    float* out = (float*)d_out;

    shab_stage<<<16, 256, 0, stream>>>(w1, b1, w2, b2, w3, b3, (unsigned char*)d_ws);

    const int B = in_sizes[0] / (S_TOK * 3);   // = 2
    shab_mfma<<<dim3(B * S_TOK * 4), 256, 0, stream>>>(coords, (const unsigned char*)d_ws, out);
}